// Round 6
// baseline (168.621 us; speedup 1.0000x reference)
//
#include <hip/hip_runtime.h>
#include <hip/hip_bf16.h>
#include <stdint.h>

#define N1 8192
#define N2 16384
#define DIM 256
#define BM 512              // rows per block = 8 waves x 64
#define CS 16               // col-splits
#define COLS (N2 / CS)      // 1024 cols per block
#define TC 32               // cols per tile (ct=2)
#define NT (COLS / TC)      // 32 tiles per block
#define NPART CS

typedef short v8s  __attribute__((ext_vector_type(8)));   // 8 x bf16 bits
typedef float f32x4 __attribute__((ext_vector_type(4)));

#define GLD16(g, l)                                                                         \
  __builtin_amdgcn_global_load_lds((const __attribute__((address_space(1))) uint32_t*)(g),  \
                                   (__attribute__((address_space(3))) uint32_t*)(l), 16, 0, 0)

__device__ __forceinline__ void top3_insert(float v, float& t0, float& t1, float& t2) {
    float nt1 = __builtin_amdgcn_fmed3f(v, t0, t1);
    float nt2 = __builtin_amdgcn_fmed3f(v, t1, t2);
    t0 = fmaxf(t0, v);
    t1 = nt1;
    t2 = nt2;
}

// 16 lanes per row, 4 rows per wave, 16 rows per block. Each lane: 4 x float4
// loads in flight (ILP), 4-step width-16 shuffle reduce, 4 x uint2 stores.
__global__ __launch_bounds__(256) void normalize_kernel(
        const float* __restrict__ inA, const float* __restrict__ inB,
        __hip_bfloat16* __restrict__ outA, __hip_bfloat16* __restrict__ outB) {
    const int wave = threadIdx.x >> 6;
    const int lane = threadIdx.x & 63;
    const int rgrp = lane >> 4;
    const int li   = lane & 15;
    const int gr   = blockIdx.x * 16 + wave * 4 + rgrp;   // 0..24575
    const float* in;
    __hip_bfloat16* out;
    int row;
    if (gr < N1) { in = inA; out = outA; row = gr; }
    else         { in = inB; out = outB; row = gr - N1; }
    const float* rp = in + (size_t)row * DIM + li * 4;
    float4 v[4];
    #pragma unroll
    for (int j = 0; j < 4; ++j) v[j] = *(const float4*)(rp + j * 64);
    float s = 0.f;
    #pragma unroll
    for (int j = 0; j < 4; ++j)
        s += v[j].x * v[j].x + v[j].y * v[j].y + v[j].z * v[j].z + v[j].w * v[j].w;
    #pragma unroll
    for (int off = 8; off; off >>= 1) s += __shfl_xor(s, off, 64);
    const float inv = 1.0f / sqrtf(s);
    __hip_bfloat16* wp = out + (size_t)row * DIM + li * 4;
    #pragma unroll
    for (int j = 0; j < 4; ++j) {
        __hip_bfloat16 o[4];
        o[0] = __float2bfloat16(v[j].x * inv);
        o[1] = __float2bfloat16(v[j].y * inv);
        o[2] = __float2bfloat16(v[j].z * inv);
        o[3] = __float2bfloat16(v[j].w * inv);
        *(uint2*)(wp + j * 64) = *(uint2*)o;
    }
}

// A-in-registers GEMM+top3, rt=4. Block = 512 rows x 1024 cols; 8 waves x 64
// rows each. Lane holds A frags af[4][8] (128 VGPR) for the whole kernel.
// KEY CHANGE vs R5: rows/wave 32->64 halves LDS-read volume per MFMA
// (reads/MFMA = 1/rt = 0.25) — R5's counters showed the shared LDS read pipe
// (8 waves x full B-tile) was the bottleneck (35% MfmaUtil + 4 conflict
// cycles/read on a saturated pipe). Per CU per 32-col tile: 128 KB LDS reads
// (~512-1024 cyc) vs 620 cyc MFMA -> compute-dominant.
// B streams through LDS: 16 KB tiles, double-buffered, staged 2 ahead,
// counted vmcnt(2) gates (never 0 until drain), 2 barriers/tile.
// cs = bid&15, bid%8 = cs%8 -> each XCD serves 2 cs-slabs (1 MB, L2-resident).
// Swizzle: col c chunk g at phys g^(c&7); same family as R0/R5.
__global__ __launch_bounds__(512, 2) void gemm_top3_kernel(
        const __hip_bfloat16* __restrict__ A, const __hip_bfloat16* __restrict__ B,
        float* __restrict__ partial) {
    __shared__ char smem[2 * 16384];   // B tile double buffer

    const int tid  = threadIdx.x;
    const int wave = tid >> 6;
    const int lane = tid & 63;
    const int lo   = lane & 15;
    const int quad = lane >> 4;
    const int cs   = blockIdx.x & 15;  // bid%8 == cs%8 -> XCD-resident B slab
    const int rb   = blockIdx.x >> 4;
    const int row0 = rb * BM;

    // ---- A fragments in registers: af[rt][s] = A[row0+wave*64+rt*16+lo][s*32+quad*8 ..+7]
    v8s af[4][8];
    {
        const char* arow = (const char*)A + (size_t)(row0 + wave * 64 + lo) * 512 + quad * 16;
        #pragma unroll
        for (int rt = 0; rt < 4; ++rt)
            #pragma unroll
            for (int s = 0; s < 8; ++s)
                af[rt][s] = *(const v8s*)(arow + rt * 8192 + s * 64);
    }
    // af loads must complete before staging so in-loop vmcnt counts are pure B.
    asm volatile("s_waitcnt vmcnt(0)" ::: "memory");

    // ---- staging constants: thread covers col j*16 + wave*2 + (lane>>5),
    // phys chunk lane&31, source logical chunk (lane&31)^(col&7) ----
    const char* Bb = (const char*)B + (size_t)cs * COLS * 512;
    int gsrc[2];
    #pragma unroll
    for (int j = 0; j < 2; ++j) {
        const int col = j * 16 + wave * 2 + (lane >> 5);
        gsrc[j] = col * 512 + (((lane & 31) ^ (col & 7)) << 4);
    }

    // ---- read-side swizzle: phys = (s*4+quad) ^ (lo&7); col base (ct*16+lo)*512 ----
    int swz[8];
    #pragma unroll
    for (int s = 0; s < 8; ++s) swz[s] = (((s * 4 + quad) ^ (lo & 7)) << 4);
    const int bco0 = lo * 512;            // ct=0
    const int bco1 = (16 + lo) * 512;     // ct=1

    float t0[16], t1[16], t2[16];
    #pragma unroll
    for (int i = 0; i < 16; ++i) { t0[i] = -1e30f; t1[i] = -1e30f; t2[i] = -1e30f; }

    // ---- prologue: stage tiles 0 and 1 ----
    #pragma unroll
    for (int j = 0; j < 2; ++j)
        GLD16(Bb + gsrc[j], smem + j * 8192 + wave * 1024);
    #pragma unroll
    for (int j = 0; j < 2; ++j)
        GLD16(Bb + 16384 + gsrc[j], smem + 16384 + j * 8192 + wave * 1024);

    #pragma unroll 2
    for (int t = 0; t < NT; ++t) {
        if (t == NT - 1) asm volatile("s_waitcnt vmcnt(0)" ::: "memory");
        else             asm volatile("s_waitcnt vmcnt(2)" ::: "memory");
        __builtin_amdgcn_s_barrier();    // all waves: tile t landed

        const char* bbuf = smem + (t & 1) * 16384;
        f32x4 acc[4][2];
        __builtin_amdgcn_s_setprio(1);
        #pragma unroll
        for (int s = 0; s < 8; ++s) {
            v8s bf0 = *(const v8s*)(bbuf + bco0 + swz[s]);
            v8s bf1 = *(const v8s*)(bbuf + bco1 + swz[s]);
            #pragma unroll
            for (int rt = 0; rt < 4; ++rt) {
                if (s == 0) {
                    acc[rt][0] = __builtin_amdgcn_mfma_f32_16x16x32_bf16(
                        af[rt][0], bf0, (f32x4){0.f, 0.f, 0.f, 0.f}, 0, 0, 0);
                    acc[rt][1] = __builtin_amdgcn_mfma_f32_16x16x32_bf16(
                        af[rt][0], bf1, (f32x4){0.f, 0.f, 0.f, 0.f}, 0, 0, 0);
                } else {
                    acc[rt][0] = __builtin_amdgcn_mfma_f32_16x16x32_bf16(
                        af[rt][s], bf0, acc[rt][0], 0, 0, 0);
                    acc[rt][1] = __builtin_amdgcn_mfma_f32_16x16x32_bf16(
                        af[rt][s], bf1, acc[rt][1], 0, 0, 0);
                }
            }
        }
        __builtin_amdgcn_s_setprio(0);
        __builtin_amdgcn_s_barrier();    // all waves done reading buf[t&1]
        if (t + 2 < NT) {                // stage t+2 into the buffer just freed
            const char* src = Bb + (size_t)(t + 2) * 16384;
            char* dst = smem + (t & 1) * 16384;
            #pragma unroll
            for (int j = 0; j < 2; ++j)
                GLD16(src + gsrc[j], dst + j * 8192 + wave * 1024);
        }
        // fold this tile's 32 C-values/lane into running top3 (VALU; hides
        // under the in-flight stage)
        #pragma unroll
        for (int rt = 0; rt < 4; ++rt)
            #pragma unroll
            for (int r = 0; r < 4; ++r) {
                const int sl = rt * 4 + r;
                top3_insert(acc[rt][0][r], t0[sl], t1[sl], t2[sl]);
                top3_insert(acc[rt][1][r], t0[sl], t1[sl], t2[sl]);
            }
    }

    // merge across the 16 lo-lanes (same row, different col residues)
    #pragma unroll
    for (int sl = 0; sl < 16; ++sl) {
        #pragma unroll
        for (int step = 1; step < 16; step <<= 1) {
            float b0 = __shfl_xor(t0[sl], step, 64);
            float b1 = __shfl_xor(t1[sl], step, 64);
            float b2 = __shfl_xor(t2[sl], step, 64);
            top3_insert(b0, t0[sl], t1[sl], t2[sl]);
            top3_insert(b1, t0[sl], t1[sl], t2[sl]);
            top3_insert(b2, t0[sl], t1[sl], t2[sl]);
        }
    }
    if (lo == 0) {
        #pragma unroll
        for (int rt = 0; rt < 4; ++rt)
            #pragma unroll
            for (int r = 0; r < 4; ++r) {
                const int row = row0 + wave * 64 + rt * 16 + quad * 4 + r;
                float* p = partial + ((size_t)row * NPART + cs) * 3;
                const int sl = rt * 4 + r;
                p[0] = t0[sl]; p[1] = t1[sl]; p[2] = t2[sl];
            }
    }
}

// 1 thread per row: 12 float4 loads (48 values), 48 inserts.
__global__ __launch_bounds__(256) void merge_kernel(
        const float* __restrict__ partial, float* __restrict__ out) {
    const int row = blockIdx.x * 256 + threadIdx.x;
    if (row >= N1) return;
    const float4* p = (const float4*)(partial + (size_t)row * NPART * 3);
    float t0 = -1e30f, t1 = -1e30f, t2 = -1e30f;
    #pragma unroll
    for (int i = 0; i < 12; ++i) {
        float4 v = p[i];
        top3_insert(v.x, t0, t1, t2);
        top3_insert(v.y, t0, t1, t2);
        top3_insert(v.z, t0, t1, t2);
        top3_insert(v.w, t0, t1, t2);
    }
    out[row] = (t0 + t1 + t2) * (1.0f / 3.0f);
}

extern "C" void kernel_launch(void* const* d_in, const int* in_sizes, int n_in,
                              void* d_out, int out_size, void* d_ws, size_t ws_size,
                              hipStream_t stream) {
    const float* tA = (const float*)d_in[0];
    const float* tB = (const float*)d_in[1];
    float* out = (float*)d_out;

    __hip_bfloat16* An = (__hip_bfloat16*)d_ws;
    __hip_bfloat16* Bn = An + (size_t)N1 * DIM;
    float* partial = (float*)(Bn + (size_t)N2 * DIM);

    normalize_kernel<<<(N1 + N2) / 16, 256, 0, stream>>>(tA, tB, An, Bn);
    gemm_top3_kernel<<<(N1 / BM) * CS, 512, 0, stream>>>(An, Bn, partial);
    merge_kernel<<<N1 / 256, 256, 0, stream>>>(partial, out);
}